// Round 1
// baseline (4489.293 us; speedup 1.0000x reference)
//
#include <hip/hip_runtime.h>
#include <hip/hip_bf16.h>
#include <cstddef>

// Problem constants
#define BB 4
#define SS 2048
#define EE 1024
#define HH 16
#define DD 64
#define FF 4096

// ---------------------------------------------------------------------------
// Generic fp32 64x64 tile GEMM helper: computes 4x4 micro-tile per thread.
// At: pointer to A[row0][0], row-major, leading dim lda
// Bt: pointer to B[0][col0], row-major, leading dim ldb
// ---------------------------------------------------------------------------
__device__ __forceinline__ void gemm_tile(const float* __restrict__ At, int lda,
                                          const float* __restrict__ Bt, int ldb,
                                          int K, float acc[4][4],
                                          float (*As)[64], float (*Bs)[64]) {
    const int tid = threadIdx.x;
    const int tr = tid >> 4, tc = tid & 15;
    const int la_m = tid >> 2;          // 0..63
    const int la_k = (tid & 3) * 4;     // 0,4,8,12
    const int lb_k = tid >> 4;          // 0..15
    const int lb_n = (tid & 15) * 4;    // 0..60

    for (int k0 = 0; k0 < K; k0 += 16) {
        float4 av = *reinterpret_cast<const float4*>(At + (size_t)la_m * lda + k0 + la_k);
        As[la_k + 0][la_m] = av.x;
        As[la_k + 1][la_m] = av.y;
        As[la_k + 2][la_m] = av.z;
        As[la_k + 3][la_m] = av.w;
        float4 bv = *reinterpret_cast<const float4*>(Bt + (size_t)(k0 + lb_k) * ldb + lb_n);
        *reinterpret_cast<float4*>(&Bs[lb_k][lb_n]) = bv;
        __syncthreads();
#pragma unroll
        for (int k = 0; k < 16; ++k) {
            float4 a = *reinterpret_cast<const float4*>(&As[k][tr * 4]);
            float4 b = *reinterpret_cast<const float4*>(&Bs[k][tc * 4]);
            float am[4] = {a.x, a.y, a.z, a.w};
            float bm[4] = {b.x, b.y, b.z, b.w};
#pragma unroll
            for (int i = 0; i < 4; ++i)
#pragma unroll
                for (int j = 0; j < 4; ++j) acc[i][j] += am[i] * bm[j];
        }
        __syncthreads();
    }
}

// ---------------------------------------------------------------------------
// QKV projection: per head h, C[s,d] = sum_e X[(b,s),e] * W[h][e][d]
// grid: (128 row-tiles, 48 = H * {Q,K,V})
// ---------------------------------------------------------------------------
__global__ __launch_bounds__(256) void qkv_kernel(const float* __restrict__ X,
                                                  const float* __restrict__ WQ,
                                                  const float* __restrict__ WK,
                                                  const float* __restrict__ WV,
                                                  float* __restrict__ Q,
                                                  float* __restrict__ K,
                                                  float* __restrict__ V) {
    __shared__ float As[16][64];
    __shared__ float Bs[16][64];
    const int mt = blockIdx.x;
    const int hz = blockIdx.y;
    const int h = hz & 15;
    const int sel = hz >> 4;
    const float* W = (sel == 0) ? WQ : (sel == 1) ? WK : WV;
    float* O = (sel == 0) ? Q : (sel == 1) ? K : V;
    const int r0 = mt * 64;
    const int b = r0 >> 11;        // r0 / 2048
    const int s0 = r0 & 2047;

    float acc[4][4] = {};
    gemm_tile(X + (size_t)r0 * EE, EE, W + (size_t)h * EE * DD, DD, EE, acc, As, Bs);

    const int tid = threadIdx.x;
    const int tr = tid >> 4, tc = tid & 15;
    float* Ob = O + (((size_t)b * HH + h) * SS + s0) * DD;
#pragma unroll
    for (int i = 0; i < 4; ++i) {
        float4 v;
        v.x = acc[i][0]; v.y = acc[i][1]; v.z = acc[i][2]; v.w = acc[i][3];
        *reinterpret_cast<float4*>(Ob + (size_t)(tr * 4 + i) * DD + tc * 4) = v;
    }
}

// ---------------------------------------------------------------------------
// Transposed 64x64 tile loader: dst[d][row] = src[row][d], src leading dim 64
// ---------------------------------------------------------------------------
__device__ __forceinline__ void load_tileT(const float* __restrict__ src,
                                           float (*dst)[68], int tid) {
    const int rr = tid >> 4;
    const int d4 = (tid & 15) * 4;
#pragma unroll
    for (int r = 0; r < 4; ++r) {
        const int row = rr + r * 16;
        float4 v = *reinterpret_cast<const float4*>(src + (size_t)row * 64 + d4);
        dst[d4 + 0][row] = v.x;
        dst[d4 + 1][row] = v.y;
        dst[d4 + 2][row] = v.z;
        dst[d4 + 3][row] = v.w;
    }
}

// ---------------------------------------------------------------------------
// Pass 1: column-softmax stats. For each (b,h) and key column t:
//   m_t = max_s scores[s,t], l_t = sum_s exp(scores[s,t]-m_t)
// grid: (32 t-tiles, 64 bh)
// ---------------------------------------------------------------------------
__global__ __launch_bounds__(256) void stats_kernel(const float* __restrict__ Q,
                                                    const float* __restrict__ Kg,
                                                    float* __restrict__ Ms,
                                                    float* __restrict__ Ls) {
    __shared__ float Qt[64][68];   // [d][s]
    __shared__ float Kt[64][68];   // [d][t]
    const int tt = blockIdx.x;
    const int bh = blockIdx.y;
    const int tid = threadIdx.x;
    const int tr = tid >> 4, tc = tid & 15;
    const float* Qb = Q + (size_t)bh * SS * DD;
    const float* Kb = Kg + (size_t)bh * SS * DD + (size_t)tt * 64 * DD;

    load_tileT(Kb, Kt, tid);

    float mloc[4] = {-1e30f, -1e30f, -1e30f, -1e30f};
    float lloc[4] = {0.f, 0.f, 0.f, 0.f};

    for (int st = 0; st < 32; ++st) {
        __syncthreads();   // protects Qt from previous iter reads; publishes Kt on st==0
        load_tileT(Qb + (size_t)st * 64 * DD, Qt, tid);
        __syncthreads();
        float sc[4][4] = {};
#pragma unroll 8
        for (int k = 0; k < 64; ++k) {
            float4 a = *reinterpret_cast<const float4*>(&Qt[k][tr * 4]);
            float4 b = *reinterpret_cast<const float4*>(&Kt[k][tc * 4]);
            float am[4] = {a.x, a.y, a.z, a.w};
            float bm[4] = {b.x, b.y, b.z, b.w};
#pragma unroll
            for (int i = 0; i < 4; ++i)
#pragma unroll
                for (int j = 0; j < 4; ++j) sc[i][j] += am[i] * bm[j];
        }
#pragma unroll
        for (int j = 0; j < 4; ++j) {
            float mt = fmaxf(fmaxf(sc[0][j], sc[1][j]), fmaxf(sc[2][j], sc[3][j]));
            float nm = fmaxf(mloc[j], mt);
            float add = __expf(sc[0][j] - nm) + __expf(sc[1][j] - nm) +
                        __expf(sc[2][j] - nm) + __expf(sc[3][j] - nm);
            lloc[j] = lloc[j] * __expf(mloc[j] - nm) + add;
            mloc[j] = nm;
        }
    }
    __syncthreads();
    float* RM = &Qt[0][0];   // reuse LDS: 16x64 partials
    float* RL = &Kt[0][0];
#pragma unroll
    for (int j = 0; j < 4; ++j) {
        RM[tr * 64 + tc * 4 + j] = mloc[j];
        RL[tr * 64 + tc * 4 + j] = lloc[j];
    }
    __syncthreads();
    if (tid < 64) {
        float m = -1e30f;
        for (int i = 0; i < 16; ++i) m = fmaxf(m, RM[i * 64 + tid]);
        float l = 0.f;
        for (int i = 0; i < 16; ++i) l += RL[i * 64 + tid] * __expf(RM[i * 64 + tid] - m);
        Ms[(size_t)bh * SS + tt * 64 + tid] = m;
        Ls[(size_t)bh * SS + tt * 64 + tid] = l;
    }
}

// ---------------------------------------------------------------------------
// Pass 2: vec[s,d] = sum_t (exp(scores[s,t]-m_t)/l_t/8) * V[t,d]
// Output written directly in att_vec layout [B,S,H*D].
// grid: (32 s-tiles, 64 bh)
// ---------------------------------------------------------------------------
__global__ __launch_bounds__(256) void pv_kernel(const float* __restrict__ Q,
                                                 const float* __restrict__ Kg,
                                                 const float* __restrict__ V,
                                                 const float* __restrict__ Ms,
                                                 const float* __restrict__ Ls,
                                                 float* __restrict__ Out) {
    __shared__ float Qt[64][68];   // [d][s]
    __shared__ float KV[64][68];   // Kt [d][t], then V [t][d]
    __shared__ float AT[64][68];   // attT [t][s]
    const int st = blockIdx.x;
    const int bh = blockIdx.y;
    const int b = bh >> 4, h = bh & 15;
    const int tid = threadIdx.x;
    const int tr = tid >> 4, tc = tid & 15;
    const float* Qb = Q + (size_t)bh * SS * DD + (size_t)st * 64 * DD;
    const float* Kb = Kg + (size_t)bh * SS * DD;
    const float* Vb = V + (size_t)bh * SS * DD;

    load_tileT(Qb, Qt, tid);

    float acc[4][4] = {};
    for (int tt = 0; tt < 32; ++tt) {
        __syncthreads();   // protect KV/AT from prev iter reads; publish Qt on tt==0
        load_tileT(Kb + (size_t)tt * 64 * DD, KV, tid);
        __syncthreads();
        float sc[4][4] = {};
#pragma unroll 8
        for (int k = 0; k < 64; ++k) {
            float4 a = *reinterpret_cast<const float4*>(&Qt[k][tr * 4]);
            float4 b2 = *reinterpret_cast<const float4*>(&KV[k][tc * 4]);
            float am[4] = {a.x, a.y, a.z, a.w};
            float bm[4] = {b2.x, b2.y, b2.z, b2.w};
#pragma unroll
            for (int i = 0; i < 4; ++i)
#pragma unroll
                for (int j = 0; j < 4; ++j) sc[i][j] += am[i] * bm[j];
        }
        float mcol[4], rl[4];
#pragma unroll
        for (int j = 0; j < 4; ++j) {
            const size_t idx = (size_t)bh * SS + tt * 64 + tc * 4 + j;
            mcol[j] = Ms[idx];
            rl[j] = 0.125f / Ls[idx];
        }
        __syncthreads();   // Kt reads done before overwriting KV with V
        // store att transposed: AT[t][s]
#pragma unroll
        for (int i = 0; i < 4; ++i)
#pragma unroll
            for (int j = 0; j < 4; ++j)
                AT[tc * 4 + j][tr * 4 + i] = __expf(sc[i][j] - mcol[j]) * rl[j];
        // load V tile (non-transposed): KV[t][d]
        {
            const int rr = tid >> 4;
            const int d4 = (tid & 15) * 4;
            const float* Vt = Vb + (size_t)tt * 64 * DD;
#pragma unroll
            for (int r = 0; r < 4; ++r) {
                const int row = rr + r * 16;
                *reinterpret_cast<float4*>(&KV[row][d4]) =
                    *reinterpret_cast<const float4*>(Vt + (size_t)row * 64 + d4);
            }
        }
        __syncthreads();
#pragma unroll 8
        for (int k = 0; k < 64; ++k) {
            float4 a = *reinterpret_cast<const float4*>(&AT[k][tr * 4]);
            float4 b2 = *reinterpret_cast<const float4*>(&KV[k][tc * 4]);
            float am[4] = {a.x, a.y, a.z, a.w};
            float bm[4] = {b2.x, b2.y, b2.z, b2.w};
#pragma unroll
            for (int i = 0; i < 4; ++i)
#pragma unroll
                for (int j = 0; j < 4; ++j) acc[i][j] += am[i] * bm[j];
        }
    }
    // write to att_vec layout [B,S,H*D]
    const int s0 = st * 64;
    float* Ob = Out + ((size_t)b * SS + s0) * (HH * DD) + h * DD;
#pragma unroll
    for (int i = 0; i < 4; ++i) {
        float4 v;
        v.x = acc[i][0]; v.y = acc[i][1]; v.z = acc[i][2]; v.w = acc[i][3];
        *reinterpret_cast<float4*>(Ob + (size_t)(tr * 4 + i) * (HH * DD) + tc * 4) = v;
    }
}

// ---------------------------------------------------------------------------
// Generic GEMM with epilogue: C = A @ B (+bias) (+resid) (relu)
// A [M,K] lda=K; B [K,N] ldb=N; C [M,N]; resid [M,N]
// grid: (M/64, N/64)
// ---------------------------------------------------------------------------
template <bool RELU>
__global__ __launch_bounds__(256) void gemm_ep(const float* __restrict__ A,
                                               const float* __restrict__ Bm,
                                               float* __restrict__ C,
                                               int K, int N,
                                               const float* __restrict__ bias,
                                               const float* __restrict__ resid) {
    __shared__ float As[16][64];
    __shared__ float Bs[16][64];
    const int r0 = blockIdx.x * 64;
    const int n0 = blockIdx.y * 64;
    const int tid = threadIdx.x;
    const int tr = tid >> 4, tc = tid & 15;

    float acc[4][4] = {};
    gemm_tile(A + (size_t)r0 * K, K, Bm + n0, N, K, acc, As, Bs);

    float bi[4] = {0.f, 0.f, 0.f, 0.f};
    if (bias) {
        float4 bv = *reinterpret_cast<const float4*>(bias + n0 + tc * 4);
        bi[0] = bv.x; bi[1] = bv.y; bi[2] = bv.z; bi[3] = bv.w;
    }
#pragma unroll
    for (int i = 0; i < 4; ++i) {
        const int row = r0 + tr * 4 + i;
        float4 rv = {0.f, 0.f, 0.f, 0.f};
        if (resid) rv = *reinterpret_cast<const float4*>(resid + (size_t)row * N + n0 + tc * 4);
        float4 o;
        o.x = acc[i][0] + bi[0] + rv.x;
        o.y = acc[i][1] + bi[1] + rv.y;
        o.z = acc[i][2] + bi[2] + rv.z;
        o.w = acc[i][3] + bi[3] + rv.w;
        if (RELU) {
            o.x = fmaxf(o.x, 0.f); o.y = fmaxf(o.y, 0.f);
            o.z = fmaxf(o.z, 0.f); o.w = fmaxf(o.w, 0.f);
        }
        *reinterpret_cast<float4*>(C + (size_t)row * N + n0 + tc * 4) = o;
    }
}

// ---------------------------------------------------------------------------
// In-place LayerNorm over last dim (E=1024). grid: B*S blocks, 256 threads.
// ---------------------------------------------------------------------------
__global__ __launch_bounds__(256) void ln_kernel(float* __restrict__ buf,
                                                 const float* __restrict__ g,
                                                 const float* __restrict__ be) {
    const int row = blockIdx.x;
    const int tid = threadIdx.x;
    float* p = buf + (size_t)row * EE;
    float4 x = reinterpret_cast<float4*>(p)[tid];
    float s = x.x + x.y + x.z + x.w;
    __shared__ float red[4];
#pragma unroll
    for (int o = 32; o > 0; o >>= 1) s += __shfl_down(s, o);
    const int wid = tid >> 6, lane = tid & 63;
    if (lane == 0) red[wid] = s;
    __syncthreads();
    const float mu = (red[0] + red[1] + red[2] + red[3]) * (1.0f / EE);
    __syncthreads();
    const float dx = x.x - mu, dy = x.y - mu, dz = x.z - mu, dw = x.w - mu;
    float v = dx * dx + dy * dy + dz * dz + dw * dw;
#pragma unroll
    for (int o = 32; o > 0; o >>= 1) v += __shfl_down(v, o);
    if (lane == 0) red[wid] = v;
    __syncthreads();
    const float var = (red[0] + red[1] + red[2] + red[3]) * (1.0f / EE);
    const float rs = rsqrtf(var + 1e-5f);
    float4 gv = reinterpret_cast<const float4*>(g)[tid];
    float4 bv = reinterpret_cast<const float4*>(be)[tid];
    float4 y;
    y.x = dx * rs * gv.x + bv.x;
    y.y = dy * rs * gv.y + bv.y;
    y.z = dz * rs * gv.z + bv.z;
    y.w = dw * rs * gv.w + bv.w;
    reinterpret_cast<float4*>(p)[tid] = y;
}

// ---------------------------------------------------------------------------
extern "C" void kernel_launch(void* const* d_in, const int* in_sizes, int n_in,
                              void* d_out, int out_size, void* d_ws, size_t ws_size,
                              hipStream_t stream) {
    const float* X     = (const float*)d_in[0];
    const float* WQ    = (const float*)d_in[1];
    const float* WK    = (const float*)d_in[2];
    const float* WV    = (const float*)d_in[3];
    const float* WO    = (const float*)d_in[4];
    const float* gamma = (const float*)d_in[5];
    const float* beta  = (const float*)d_in[6];
    const float* W1    = (const float*)d_in[7];
    const float* b1    = (const float*)d_in[8];
    const float* W2    = (const float*)d_in[9];
    const float* b2    = (const float*)d_in[10];
    float* out = (float*)d_out;

    const size_t NT = (size_t)BB * SS;          // 8192 tokens
    const size_t QKV = (size_t)BB * HH * SS * DD;   // 8388608
    float* ws = (float*)d_ws;
    float* Q    = ws;
    float* K    = Q + QKV;
    float* V    = K + QKV;
    float* vec  = V + QKV;          // att_vec [B,S,H*D]
    float* vatt = vec + QKV;        // vector_att [B,S,E]
    float* Ms   = vatt + QKV;       // [B*H, S]
    float* Ls   = Ms + (size_t)BB * HH * SS;
    float* hidden = ws;             // reuse Q..vec region: 8192*4096 floats

    // 1. QKV projections
    qkv_kernel<<<dim3(NT / 64, HH * 3), 256, 0, stream>>>(X, WQ, WK, WV, Q, K, V);
    // 2. column-softmax stats
    stats_kernel<<<dim3(SS / 64, BB * HH), 256, 0, stream>>>(Q, K, Ms, Ls);
    // 3. normalize + PV, write att_vec
    pv_kernel<<<dim3(SS / 64, BB * HH), 256, 0, stream>>>(Q, K, V, Ms, Ls, vec);
    // 4. WO projection + residual X
    gemm_ep<false><<<dim3(NT / 64, EE / 64), 256, 0, stream>>>(vec, WO, vatt, EE, EE, nullptr, X);
    // 5. LayerNorm 1 (in place)
    ln_kernel<<<NT, 256, 0, stream>>>(vatt, gamma, beta);
    // 6. FFN up + relu
    gemm_ep<true><<<dim3(NT / 64, FF / 64), 256, 0, stream>>>(vatt, W1, hidden, EE, FF, b1, nullptr);
    // 7. FFN down + bias + residual vector_att -> d_out
    gemm_ep<false><<<dim3(NT / 64, EE / 64), 256, 0, stream>>>(hidden, W2, out, FF, EE, b2, vatt);
    // 8. final LayerNorm (in place on d_out)
    ln_kernel<<<NT, 256, 0, stream>>>(out, gamma, beta);
}

// Round 2
// 771.854 us; speedup vs baseline: 5.8162x; 5.8162x over previous
//
#include <hip/hip_runtime.h>
#include <cstddef>
#include <cstdint>

#define BB 4
#define SS 2048
#define EE 1024
#define HH 16
#define DD 64
#define FF 4096

typedef unsigned short u16;
typedef __attribute__((ext_vector_type(8))) short short8;   // 8 bf16 = 4 VGPR (MFMA A/B frag)
typedef __attribute__((ext_vector_type(4))) short short4v;
typedef __attribute__((ext_vector_type(4))) float f32x4;    // MFMA C/D frag

__device__ __forceinline__ u16 f2bf(float x) {
    unsigned u = __builtin_bit_cast(unsigned, x);
    u += 0x7fffu + ((u >> 16) & 1u);   // round-to-nearest-even
    return (u16)(u >> 16);
}
__device__ __forceinline__ float bf2f(u16 h) {
    unsigned u = ((unsigned)h) << 16;
    return __builtin_bit_cast(float, u);
}

// ---------------------------------------------------------------------------
// fp32 -> bf16 elementwise convert (4 elems/thread)
// ---------------------------------------------------------------------------
__global__ __launch_bounds__(256) void cvt_bf(const float* __restrict__ in,
                                              u16* __restrict__ out, int n4) {
    const int i = blockIdx.x * 256 + threadIdx.x;
    if (i < n4) {
        float4 v = reinterpret_cast<const float4*>(in)[i];
        short4v o;
        o.x = (short)f2bf(v.x); o.y = (short)f2bf(v.y);
        o.z = (short)f2bf(v.z); o.w = (short)f2bf(v.w);
        reinterpret_cast<short4v*>(out)[i] = o;
    }
}

// ---------------------------------------------------------------------------
// Transpose + convert: out[c][r] = (bf16) in[r][c].  in: [R][C] fp32, batched.
// grid (R/64, C/64, batch)
// ---------------------------------------------------------------------------
__global__ __launch_bounds__(256) void transp_bf(const float* __restrict__ in,
                                                 u16* __restrict__ out, int R, int C) {
    __shared__ float T[64][65];
    const int r0 = blockIdx.x * 64, c0 = blockIdx.y * 64;
    const size_t zoff = (size_t)blockIdx.z * R * C;
    in += zoff; out += zoff;
    const int tid = threadIdx.x;
#pragma unroll 4
    for (int i = 0; i < 16; ++i) {
        int l = tid + i * 256;
        T[l >> 6][l & 63] = in[(size_t)(r0 + (l >> 6)) * C + c0 + (l & 63)];
    }
    __syncthreads();
#pragma unroll 4
    for (int i = 0; i < 16; ++i) {
        int l = tid + i * 256;
        out[(size_t)(c0 + (l >> 6)) * R + r0 + (l & 63)] = f2bf(T[l & 63][l >> 6]);
    }
}

// ---------------------------------------------------------------------------
// bf16 MFMA GEMM, 128x128 tile, BK=32, 4 waves (each a 64x64 quadrant).
// A [M][K] bf16 row-major (k inner); BT [N][K] bf16 (k inner). C row-major ldc=N.
// EPI: 0 = bf16 out
//      1 = f32 out + f32 resid
//      2 = bf16 out + bias + relu
//      3 = f32 out + bias + bf16 resid
// ---------------------------------------------------------------------------
template <int EPI>
__global__ __launch_bounds__(256) void gemm_bf16(const u16* __restrict__ A,
                                                 const u16* __restrict__ BT,
                                                 int K, int N,
                                                 void* __restrict__ Cout,
                                                 const float* __restrict__ bias,
                                                 const void* __restrict__ resid) {
    __shared__ u16 As[128 * 40];   // +8 pad: bank-spread, 16B-aligned rows
    __shared__ u16 Bs[128 * 40];
    const int tid = threadIdx.x;
    const int w = tid >> 6, l = tid & 63;
    const int quad = l >> 4, lane16 = l & 15;
    const int wr = (w >> 1) * 64, wc = (w & 1) * 64;
    const int m0 = blockIdx.x * 128, n0 = blockIdx.y * 128;
    const u16* Ab = A + (size_t)m0 * K;
    const u16* Bb = BT + (size_t)n0 * K;

    // staging: 512 chunks of 16B per tile, 2 per thread (rows sr, sr+64)
    const int sr = tid >> 2;              // 0..63
    const int kg = (tid & 3) * 8;         // k offset 0/8/16/24
    const u16* Apt = Ab + (size_t)sr * K + kg;
    const u16* Bpt = Bb + (size_t)sr * K + kg;
    const size_t rstep = (size_t)64 * K;
    u16* AsW0 = &As[sr * 40 + kg];
    u16* AsW1 = &As[(sr + 64) * 40 + kg];
    u16* BsW0 = &Bs[sr * 40 + kg];
    u16* BsW1 = &Bs[(sr + 64) * 40 + kg];

    f32x4 acc[4][4] = {};
    short8 pa0 = *(const short8*)Apt;
    short8 pa1 = *(const short8*)(Apt + rstep);
    short8 pb0 = *(const short8*)Bpt;
    short8 pb1 = *(const short8*)(Bpt + rstep);

    for (int k0 = 0; k0 < K; k0 += 32) {
        __syncthreads();
        *(short8*)AsW0 = pa0; *(short8*)AsW1 = pa1;
        *(short8*)BsW0 = pb0; *(short8*)BsW1 = pb1;
        __syncthreads();
        if (k0 + 32 < K) {   // software-pipelined prefetch of next K-slab
            const u16* ap = Apt + k0 + 32;
            const u16* bp = Bpt + k0 + 32;
            pa0 = *(const short8*)ap; pa1 = *(const short8*)(ap + rstep);
            pb0 = *(const short8*)bp; pb1 = *(const short8*)(bp + rstep);
        }
        short8 af[4], bf[4];
#pragma unroll
        for (int mf = 0; mf < 4; ++mf)
            af[mf] = *(const short8*)&As[(wr + mf * 16 + lane16) * 40 + quad * 8];
#pragma unroll
        for (int nf = 0; nf < 4; ++nf)
            bf[nf] = *(const short8*)&Bs[(wc + nf * 16 + lane16) * 40 + quad * 8];
#pragma unroll
        for (int mf = 0; mf < 4; ++mf)
#pragma unroll
            for (int nf = 0; nf < 4; ++nf)
                acc[mf][nf] = __builtin_amdgcn_mfma_f32_16x16x32_bf16(af[mf], bf[nf], acc[mf][nf], 0, 0, 0);
    }

#pragma unroll
    for (int mf = 0; mf < 4; ++mf) {
        const int row = m0 + wr + mf * 16 + quad * 4;
#pragma unroll
        for (int nf = 0; nf < 4; ++nf) {
            const int col = n0 + wc + nf * 16 + lane16;
#pragma unroll
            for (int r = 0; r < 4; ++r) {
                float v = acc[mf][nf][r];
                const size_t idx = (size_t)(row + r) * N + col;
                if (EPI == 0) {
                    ((u16*)Cout)[idx] = f2bf(v);
                } else if (EPI == 1) {
                    ((float*)Cout)[idx] = v + ((const float*)resid)[idx];
                } else if (EPI == 2) {
                    v += bias[col];
                    ((u16*)Cout)[idx] = f2bf(fmaxf(v, 0.f));
                } else {
                    v += bias[col] + bf2f(((const u16*)resid)[idx]);
                    ((float*)Cout)[idx] = v;
                }
            }
        }
    }
}

// ---------------------------------------------------------------------------
// Pass 1: column-softmax stats via MFMA. Q,K: [B,S,H*D] bf16.
// Per block: one (bh, 64-wide t-tile); wave w owns 16 t-columns, scans all s.
// C-frag col = t = lane&15  ->  per-lane online (m,l) then cross-quad shfl.
// grid (S/64, B*H)
// ---------------------------------------------------------------------------
__global__ __launch_bounds__(256) void stats_mfma(const u16* __restrict__ Qg,
                                                  const u16* __restrict__ Kg,
                                                  float* __restrict__ Ms,
                                                  float* __restrict__ Ls) {
    __shared__ u16 Kt[64 * 72];   // [t][d], +8 pad
    __shared__ u16 Qt[64 * 72];   // [s][d]
    const int t0 = blockIdx.x * 64;
    const int bh = blockIdx.y;
    const int b = bh >> 4, h = bh & 15;
    const int tid = threadIdx.x;
    const int w = tid >> 6, l = tid & 63;
    const int quad = l >> 4, lane16 = l & 15;
    const u16* Qp = Qg + (size_t)b * SS * 1024 + h * 64;
    const u16* Kp = Kg + (size_t)b * SS * 1024 + h * 64;
    const int sr = tid >> 3;            // 0..31
    const int dg = (tid & 7) * 8;

    *(short8*)&Kt[sr * 72 + dg] = *(const short8*)(Kp + (size_t)(t0 + sr) * 1024 + dg);
    *(short8*)&Kt[(sr + 32) * 72 + dg] = *(const short8*)(Kp + (size_t)(t0 + sr + 32) * 1024 + dg);

    float mcol = -1e30f, lcol = 0.f;
    for (int st = 0; st < 32; ++st) {
        __syncthreads();
        const u16* qsrc = Qp + (size_t)(st * 64 + sr) * 1024 + dg;
        *(short8*)&Qt[sr * 72 + dg] = *(const short8*)qsrc;
        *(short8*)&Qt[(sr + 32) * 72 + dg] = *(const short8*)(qsrc + (size_t)32 * 1024);
        __syncthreads();
        f32x4 sc[4] = {};
#pragma unroll
        for (int ks = 0; ks < 2; ++ks) {
            short8 bfr = *(const short8*)&Kt[(w * 16 + lane16) * 72 + quad * 8 + ks * 32];
#pragma unroll
            for (int mf = 0; mf < 4; ++mf) {
                short8 afr = *(const short8*)&Qt[(mf * 16 + lane16) * 72 + quad * 8 + ks * 32];
                sc[mf] = __builtin_amdgcn_mfma_f32_16x16x32_bf16(afr, bfr, sc[mf], 0, 0, 0);
            }
        }
        float tmax = -1e30f;
#pragma unroll
        for (int mf = 0; mf < 4; ++mf)
#pragma unroll
            for (int r = 0; r < 4; ++r) tmax = fmaxf(tmax, sc[mf][r]);
        const float nm = fmaxf(mcol, tmax);
        float add = 0.f;
#pragma unroll
        for (int mf = 0; mf < 4; ++mf)
#pragma unroll
            for (int r = 0; r < 4; ++r) add += __expf(sc[mf][r] - nm);
        lcol = lcol * __expf(mcol - nm) + add;
        mcol = nm;
    }
    // combine the 4 quads holding the same column
#pragma unroll
    for (int off = 32; off >= 16; off >>= 1) {
        float om = __shfl_xor(mcol, off);
        float ol = __shfl_xor(lcol, off);
        float nm = fmaxf(mcol, om);
        lcol = lcol * __expf(mcol - nm) + ol * __expf(om - nm);
        mcol = nm;
    }
    if (quad == 0) {
        Ms[(size_t)bh * SS + t0 + w * 16 + lane16] = mcol;
        Ls[(size_t)bh * SS + t0 + w * 16 + lane16] = lcol;
    }
}

// ---------------------------------------------------------------------------
// Pass 2: P = exp(QK^T - m_t) * 0.125/l_t (bf16, via swizzled LDS C->A relayout),
// out = P @ V accumulated in MFMA. Vt: [H*D][B*S] bf16 (k=t contiguous).
// Output written straight into att_vec layout [B,S,H*D] bf16.
// grid (S/128, B*H)
// ---------------------------------------------------------------------------
__global__ __launch_bounds__(256) void pv_mfma(const u16* __restrict__ Qg,
                                               const u16* __restrict__ Kg,
                                               const u16* __restrict__ Vtg,
                                               const float* __restrict__ Ms,
                                               const float* __restrict__ Ls,
                                               u16* __restrict__ vecbf) {
    __shared__ u16 Qs[128 * 72];  // [s][d]
    __shared__ u16 Ks[64 * 72];   // [t][d]
    __shared__ u16 Vs[64 * 72];   // [d][t]
    __shared__ u16 Ps[128 * 64];  // [s][t], XOR-swizzled cols
    const int s0 = blockIdx.x * 128;
    const int bh = blockIdx.y;
    const int b = bh >> 4, h = bh & 15;
    const int tid = threadIdx.x;
    const int w = tid >> 6, l = tid & 63;
    const int quad = l >> 4, lane16 = l & 15;
    const u16* Qp = Qg + (size_t)b * SS * 1024 + h * 64;
    const u16* Kp = Kg + (size_t)b * SS * 1024 + h * 64;
    const u16* Vp = Vtg + (size_t)h * 64 * 8192 + (size_t)b * SS;
    const int sr8 = tid >> 3, dg = (tid & 7) * 8;

#pragma unroll
    for (int i = 0; i < 4; ++i)
        *(short8*)&Qs[(sr8 + i * 32) * 72 + dg] =
            *(const short8*)(Qp + (size_t)(s0 + sr8 + i * 32) * 1024 + dg);

    f32x4 acc[2][4] = {};
    for (int tt = 0; tt < 32; ++tt) {
        const int t0 = tt * 64;
        __syncthreads();   // all waves done reading Ks/Vs of prev iter
        *(short8*)&Ks[sr8 * 72 + dg] = *(const short8*)(Kp + (size_t)(t0 + sr8) * 1024 + dg);
        *(short8*)&Ks[(sr8 + 32) * 72 + dg] = *(const short8*)(Kp + (size_t)(t0 + sr8 + 32) * 1024 + dg);
        *(short8*)&Vs[sr8 * 72 + dg] = *(const short8*)(Vp + (size_t)sr8 * 8192 + t0 + dg);
        *(short8*)&Vs[(sr8 + 32) * 72 + dg] = *(const short8*)(Vp + (size_t)(sr8 + 32) * 8192 + t0 + dg);
        __syncthreads();
        // ---- QK^T: wave w covers s rows [w*32, w*32+32), all 64 t
        f32x4 sc[2][4] = {};
#pragma unroll
        for (int ks = 0; ks < 2; ++ks) {
            short8 afr[2];
#pragma unroll
            for (int mf = 0; mf < 2; ++mf)
                afr[mf] = *(const short8*)&Qs[(w * 32 + mf * 16 + lane16) * 72 + quad * 8 + ks * 32];
#pragma unroll
            for (int nf = 0; nf < 4; ++nf) {
                short8 bfr = *(const short8*)&Ks[(nf * 16 + lane16) * 72 + quad * 8 + ks * 32];
                sc[0][nf] = __builtin_amdgcn_mfma_f32_16x16x32_bf16(afr[0], bfr, sc[0][nf], 0, 0, 0);
                sc[1][nf] = __builtin_amdgcn_mfma_f32_16x16x32_bf16(afr[1], bfr, sc[1][nf], 0, 0, 0);
            }
        }
        // ---- normalize with column stats, store P (C-layout -> LDS [s][t])
#pragma unroll
        for (int nf = 0; nf < 4; ++nf) {
            const size_t sidx = (size_t)bh * SS + t0 + nf * 16 + lane16;
            const float mt = Ms[sidx];
            const float rl = 0.125f / Ls[sidx];
            const int scol = (nf * 16 + lane16) ^ (quad << 4);
#pragma unroll
            for (int mf = 0; mf < 2; ++mf)
#pragma unroll
                for (int r = 0; r < 4; ++r) {
                    const int row = w * 32 + mf * 16 + quad * 4 + r;
                    Ps[row * 64 + scol] = f2bf(__expf(sc[mf][nf][r] - mt) * rl);
                }
        }
        // Ps rows [w*32,w*32+32) are wave-local: no barrier needed before reading
        const int sw = ((lane16 >> 2) & 3) << 4;
#pragma unroll
        for (int ks = 0; ks < 2; ++ks) {
            short8 bfr[4];
#pragma unroll
            for (int nf = 0; nf < 4; ++nf)
                bfr[nf] = *(const short8*)&Vs[(nf * 16 + lane16) * 72 + quad * 8 + ks * 32];
#pragma unroll
            for (int mf = 0; mf < 2; ++mf) {
                const int prow = w * 32 + mf * 16 + lane16;
                const int pcol = (quad * 8 + ks * 32) ^ sw;
                short8 afr = *(const short8*)&Ps[prow * 64 + pcol];
#pragma unroll
                for (int nf = 0; nf < 4; ++nf)
                    acc[mf][nf] = __builtin_amdgcn_mfma_f32_16x16x32_bf16(afr, bfr[nf], acc[mf][nf], 0, 0, 0);
            }
        }
    }
#pragma unroll
    for (int mf = 0; mf < 2; ++mf)
#pragma unroll
        for (int nf = 0; nf < 4; ++nf) {
            const int col = h * 64 + nf * 16 + lane16;
#pragma unroll
            for (int r = 0; r < 4; ++r) {
                const int srow = s0 + w * 32 + mf * 16 + quad * 4 + r;
                vecbf[(size_t)(b * SS + srow) * 1024 + col] = f2bf(acc[mf][nf][r]);
            }
        }
}

// ---------------------------------------------------------------------------
// LayerNorm over last dim (E=1024), fp32 in -> bf16 out (separate buffer)
// ---------------------------------------------------------------------------
__global__ __launch_bounds__(256) void ln_bf_kernel(const float* __restrict__ buf,
                                                    const float* __restrict__ g,
                                                    const float* __restrict__ be,
                                                    u16* __restrict__ outbf) {
    const int row = blockIdx.x;
    const int tid = threadIdx.x;
    const float* p = buf + (size_t)row * EE;
    float4 x = reinterpret_cast<const float4*>(p)[tid];
    float s = x.x + x.y + x.z + x.w;
    __shared__ float red[4];
#pragma unroll
    for (int o = 32; o > 0; o >>= 1) s += __shfl_down(s, o);
    const int wid = tid >> 6, lane = tid & 63;
    if (lane == 0) red[wid] = s;
    __syncthreads();
    const float mu = (red[0] + red[1] + red[2] + red[3]) * (1.0f / EE);
    __syncthreads();
    const float dx = x.x - mu, dy = x.y - mu, dz = x.z - mu, dw = x.w - mu;
    float v = dx * dx + dy * dy + dz * dz + dw * dw;
#pragma unroll
    for (int o = 32; o > 0; o >>= 1) v += __shfl_down(v, o);
    if (lane == 0) red[wid] = v;
    __syncthreads();
    const float var = (red[0] + red[1] + red[2] + red[3]) * (1.0f / EE);
    const float rs = rsqrtf(var + 1e-5f);
    float4 gv = reinterpret_cast<const float4*>(g)[tid];
    float4 bv = reinterpret_cast<const float4*>(be)[tid];
    short4v o;
    o.x = (short)f2bf(dx * rs * gv.x + bv.x);
    o.y = (short)f2bf(dy * rs * gv.y + bv.y);
    o.z = (short)f2bf(dz * rs * gv.z + bv.z);
    o.w = (short)f2bf(dw * rs * gv.w + bv.w);
    reinterpret_cast<short4v*>(outbf + (size_t)row * EE)[tid] = o;
}

// In-place fp32 LayerNorm (final output)
__global__ __launch_bounds__(256) void ln_kernel(float* __restrict__ buf,
                                                 const float* __restrict__ g,
                                                 const float* __restrict__ be) {
    const int row = blockIdx.x;
    const int tid = threadIdx.x;
    float* p = buf + (size_t)row * EE;
    float4 x = reinterpret_cast<float4*>(p)[tid];
    float s = x.x + x.y + x.z + x.w;
    __shared__ float red[4];
#pragma unroll
    for (int o = 32; o > 0; o >>= 1) s += __shfl_down(s, o);
    const int wid = tid >> 6, lane = tid & 63;
    if (lane == 0) red[wid] = s;
    __syncthreads();
    const float mu = (red[0] + red[1] + red[2] + red[3]) * (1.0f / EE);
    __syncthreads();
    const float dx = x.x - mu, dy = x.y - mu, dz = x.z - mu, dw = x.w - mu;
    float v = dx * dx + dy * dy + dz * dz + dw * dw;
#pragma unroll
    for (int o = 32; o > 0; o >>= 1) v += __shfl_down(v, o);
    if (lane == 0) red[wid] = v;
    __syncthreads();
    const float var = (red[0] + red[1] + red[2] + red[3]) * (1.0f / EE);
    const float rs = rsqrtf(var + 1e-5f);
    float4 gv = reinterpret_cast<const float4*>(g)[tid];
    float4 bv = reinterpret_cast<const float4*>(be)[tid];
    float4 y;
    y.x = dx * rs * gv.x + bv.x;
    y.y = dy * rs * gv.y + bv.y;
    y.z = dz * rs * gv.z + bv.z;
    y.w = dw * rs * gv.w + bv.w;
    reinterpret_cast<float4*>(p)[tid] = y;
}

// ---------------------------------------------------------------------------
extern "C" void kernel_launch(void* const* d_in, const int* in_sizes, int n_in,
                              void* d_out, int out_size, void* d_ws, size_t ws_size,
                              hipStream_t stream) {
    const float* X     = (const float*)d_in[0];
    const float* WQ    = (const float*)d_in[1];
    const float* WK    = (const float*)d_in[2];
    const float* WV    = (const float*)d_in[3];
    const float* WO    = (const float*)d_in[4];
    const float* gamma = (const float*)d_in[5];
    const float* beta  = (const float*)d_in[6];
    const float* W1    = (const float*)d_in[7];
    const float* b1    = (const float*)d_in[8];
    const float* W2    = (const float*)d_in[9];
    const float* b2    = (const float*)d_in[10];
    float* out = (float*)d_out;

    char* ws = (char*)d_ws;
    const size_t MB = 1024 * 1024;
    u16* Qbf   = (u16*)(ws + 0);          // 16 MB [B*S][H*D]
    u16* Kbf   = (u16*)(ws + 16 * MB);    // 16 MB
    u16* Vt    = (u16*)(ws + 32 * MB);    // 16 MB [H*D][B*S]
    u16* vecbf = (u16*)(ws + 48 * MB);    // 16 MB att_vec bf16
    u16* hid   = (u16*)(ws + 0);          // 64 MB, overlays Q/K/Vt/vec (dead by FFN1)
    u16* Xbf   = (u16*)(ws + 64 * MB);    // 16 MB
    u16* WQT   = (u16*)(ws + 80 * MB);    // 2 MB  [H*D][E]
    u16* WKT   = (u16*)(ws + 82 * MB);
    u16* WVT   = (u16*)(ws + 84 * MB);
    u16* WOT   = (u16*)(ws + 86 * MB);    // 2 MB  [E][H*D]
    u16* W1T   = (u16*)(ws + 88 * MB);    // 8 MB  [F][E]
    u16* W2T   = (u16*)(ws + 96 * MB);    // 8 MB  [E][F]
    float* Ms  = (float*)(ws + 104 * MB); // 512 KB
    float* Ls  = (float*)(ws + 104 * MB + 512 * 1024);
    float* vatt  = (float*)(ws + 105 * MB); // 32 MB fp32 (pre-LN1)
    u16*   ln1bf = (u16*)(ws + 137 * MB);   // 16 MB LN1 output (FFN in + resid)

    const int NT = BB * SS;   // 8192 tokens

    // --- one-time converts / weight transposes (bf16, k-innermost) ---
    cvt_bf<<<8192, 256, 0, stream>>>(X, Xbf, NT * EE / 4);
    transp_bf<<<dim3(16, 1, 16), 256, 0, stream>>>(WQ, WQT, EE, DD);
    transp_bf<<<dim3(16, 1, 16), 256, 0, stream>>>(WK, WKT, EE, DD);
    transp_bf<<<dim3(16, 1, 16), 256, 0, stream>>>(WV, WVT, EE, DD);
    transp_bf<<<dim3(16, 16, 1), 256, 0, stream>>>(WO, WOT, HH * DD, EE);
    transp_bf<<<dim3(16, 64, 1), 256, 0, stream>>>(W1, W1T, EE, FF);
    transp_bf<<<dim3(64, 16, 1), 256, 0, stream>>>(W2, W2T, FF, EE);

    // --- projections (Q,K normal layout; V produced transposed) ---
    gemm_bf16<0><<<dim3(64, 8), 256, 0, stream>>>(Xbf, WQT, EE, 1024, Qbf, nullptr, nullptr);
    gemm_bf16<0><<<dim3(64, 8), 256, 0, stream>>>(Xbf, WKT, EE, 1024, Kbf, nullptr, nullptr);
    gemm_bf16<0><<<dim3(8, 64), 256, 0, stream>>>(WVT, Xbf, EE, 8192, Vt, nullptr, nullptr);

    // --- attention (column softmax then /8) ---
    stats_mfma<<<dim3(SS / 64, BB * HH), 256, 0, stream>>>(Qbf, Kbf, Ms, Ls);
    pv_mfma<<<dim3(SS / 128, BB * HH), 256, 0, stream>>>(Qbf, Kbf, Vt, Ms, Ls, vecbf);

    // --- WO + residual X -> vatt (fp32), LN1 -> ln1bf ---
    gemm_bf16<1><<<dim3(64, 8), 256, 0, stream>>>(vecbf, WOT, EE, 1024, vatt, nullptr, X);
    ln_bf_kernel<<<NT, 256, 0, stream>>>(vatt, gamma, beta, ln1bf);

    // --- FFN ---
    gemm_bf16<2><<<dim3(64, 32), 256, 0, stream>>>(ln1bf, W1T, EE, FF, hid, b1, nullptr);
    gemm_bf16<3><<<dim3(64, 8), 256, 0, stream>>>(hid, W2T, FF, 1024, out, b2, ln1bf);

    // --- final LN in place on d_out ---
    ln_kernel<<<NT, 256, 0, stream>>>(out, gamma, beta);
}